// Round 1
// baseline (356.186 us; speedup 1.0000x reference)
//
#include <hip/hip_runtime.h>
#include <hip/hip_bf16.h>

#define N_NODES 100000
#define N_EDGES 1600000
#define FEAT 128
#define N_GRAPHS 1024
#define NBUCK 391   // ceil(N_NODES/256) windows of 256 nodes (bucket = dst >> 8)
#define CHUNK 4096  // edges per k_bucket block
#define NTILES 1563 // ceil(N_NODES/64) gemm row tiles
#define G1A 781     // gemm1 tiles overlapped with bucket
#define G1B 782     // gemm1 tiles overlapped with bfill

typedef short short8 __attribute__((ext_vector_type(8)));
typedef float float4v __attribute__((ext_vector_type(4)));

static __device__ inline unsigned short f2bf(float f) {
    __hip_bfloat16 b = __float2bfloat16(f);
    unsigned short r;
    __builtin_memcpy(&r, &b, 2);
    return r;
}
static __device__ inline float bf_lo(unsigned int v) { return __uint_as_float(v << 16); }
static __device__ inline float bf_hi(unsigned int v) { return __uint_as_float(v & 0xFFFF0000u); }
static __device__ inline float bf_s(unsigned short s) { return __uint_as_float(((unsigned)s) << 16); }

// ---------------- dispatch 1: W-split prep (blocks 0..127) + dst histogram (blocks 128..383) ----------
__global__ __launch_bounds__(256) void k_prep_hist(const float* __restrict__ W1,
                                                   const float* __restrict__ W2,
                                                   unsigned short* __restrict__ wp1,
                                                   unsigned short* __restrict__ wp2,
                                                   const int* __restrict__ dst,
                                                   int* __restrict__ bcount,
                                                   unsigned int* __restrict__ udummy,
                                                   float* __restrict__ dinv) {
    int bid = blockIdx.x;
    if (bid < 128) {
        const float* W = (bid < 64) ? W1 : W2;
        unsigned short* wp = (bid < 64) ? wp1 : wp2;
        int t = (bid & 63) * 256 + threadIdx.x;  // 0..16383
        int k = t >> 7, n = t & 127;
        float w = W[k * 128 + n];
        unsigned ub = __float_as_uint(w);
        unsigned short hi = (unsigned short)(ub >> 16);  // truncation split
        float hif = __uint_as_float(ub & 0xFFFF0000u);
        unsigned short lo = f2bf(w - hif);               // RNE residual
        int sidx = n * 128 + ((k & 7) | (8 * (((k >> 3) ^ n) & 15)));
        wp[sidx] = hi;
        wp[16384 + sidx] = lo;
        if (bid == 0) {
            if (threadIdx.x < 64) udummy[threadIdx.x] = 0;
            if (threadIdx.x == 64) dinv[N_NODES] = 0.f;
        }
    } else {
        __shared__ int h[NBUCK];
        for (int i = threadIdx.x; i < NBUCK; i += 256) h[i] = 0;
        __syncthreads();
        int hb = bid - 128;
        for (int e = hb * 256 + threadIdx.x; e < N_EDGES; e += 256 * 256)
            atomicAdd(&h[dst[e] >> 8], 1);
        __syncthreads();
        for (int i = threadIdx.x; i < NBUCK; i += 256) {
            int c = h[i];
            if (c) atomicAdd(&bcount[i], c);
        }
    }
}

// ---------------- dispatch 2: exclusive scan of 391 bucket counts (single block) ----------------
// bbase doubles as the CSR window base (wbase==bbase: per-bucket deg sum == bucket edge count).
__global__ __launch_bounds__(512) void k_scan391(const int* __restrict__ in,
                                                 int* __restrict__ base,
                                                 int* __restrict__ cur,
                                                 int* __restrict__ tail) {
    int t = threadIdx.x;
    int v = (t < NBUCK) ? in[t] : 0;
    int lane = t & 63, wid = t >> 6;
    int s = v;
#pragma unroll
    for (int d = 1; d < 64; d <<= 1) { int n = __shfl_up(s, d); if (lane >= d) s += n; }
    __shared__ int ws[8];
    if (lane == 63) ws[wid] = s;
    __syncthreads();
    if (t < 8) {
        int x = ws[t];
#pragma unroll
        for (int d = 1; d < 8; d <<= 1) { int n = __shfl_up(x, d); if ((int)t >= d) x += n; }
        ws[t] = x;
    }
    __syncthreads();
    int excl = s - v + (wid ? ws[wid - 1] : 0);
    if (t < NBUCK) {
        base[t] = excl;
        cur[t] = excl;
    }
    if (t == 0) tail[0] = N_EDGES;
}

// ---------------- shared gemm body: u = bf16(inp @ W) (UNSCALED — dinv applied in agg) ----------------
__device__ __forceinline__ void gemm_f32_body(int tile, const float* __restrict__ inp,
                                              const unsigned short* __restrict__ wp,
                                              unsigned short* __restrict__ u) {
    __shared__ unsigned short sW[32768];  // 64 KB: hi | lo (swizzled)
    {
        float4* d4 = (float4*)sW;
        const float4* s4 = (const float4*)wp;
#pragma unroll
        for (int i = 0; i < 16; ++i) d4[threadIdx.x + 256 * i] = s4[threadIdx.x + 256 * i];
    }
    __syncthreads();
    const int t = threadIdx.x;
    const int wv = t >> 6, L = t & 63;
    const int m = L & 15, q = L >> 4;
    const int r0 = tile * 64 + wv * 16;
    int arow = r0 + m;
    if (arow >= N_NODES) arow = N_NODES - 1;
    const float4* ap = (const float4*)(inp + (size_t)arow * 128);
    float4v acc[8];
#pragma unroll
    for (int c = 0; c < 8; ++c) acc[c] = (float4v){0.f, 0.f, 0.f, 0.f};
#pragma unroll
    for (int k0 = 0; k0 < 128; k0 += 32) {
        float4 f0 = ap[(k0 >> 2) + 2 * q];
        float4 f1 = ap[(k0 >> 2) + 2 * q + 1];
        float fa[8] = {f0.x, f0.y, f0.z, f0.w, f1.x, f1.y, f1.z, f1.w};
        short8 ah, al;
#pragma unroll
        for (int j = 0; j < 8; ++j) {
            unsigned ub = __float_as_uint(fa[j]);
            ah[j] = (short)(ub >> 16);
            float hif = __uint_as_float(ub & 0xFFFF0000u);
            al[j] = (short)f2bf(fa[j] - hif);
        }
        const int b = (k0 >> 3) + q;
#pragma unroll
        for (int c = 0; c < 8; ++c) {
            int ng = c * 16 + m;
            int elem = ng * 128 + 8 * ((b ^ ng) & 15);
            short8 bh = *(const short8*)&sW[elem];
            short8 bl = *(const short8*)&sW[16384 + elem];
            acc[c] = __builtin_amdgcn_mfma_f32_16x16x32_bf16(ah, bh, acc[c], 0, 0, 0);
            acc[c] = __builtin_amdgcn_mfma_f32_16x16x32_bf16(al, bh, acc[c], 0, 0, 0);
            acc[c] = __builtin_amdgcn_mfma_f32_16x16x32_bf16(ah, bl, acc[c], 0, 0, 0);
        }
    }
#pragma unroll
    for (int r = 0; r < 4; ++r) {
        int row = r0 + 4 * q + r;
        if (row < N_NODES) {
            unsigned short* up = u + (size_t)row * 128 + m;
#pragma unroll
            for (int c = 0; c < 8; ++c) up[c * 16] = f2bf(acc[c][r]);
        }
    }
}

// ---------------- dispatch 3: bucket binning (blocks 0..390) + gemm1 tiles 0..780 ----------------
__global__ __launch_bounds__(256) void k_bucket_g1(const int* __restrict__ src,
                                                   const int* __restrict__ dst,
                                                   int* __restrict__ bcur,
                                                   unsigned int* __restrict__ pairs,
                                                   const float* __restrict__ x,
                                                   const unsigned short* __restrict__ wp1,
                                                   unsigned short* __restrict__ u) {
    if (blockIdx.x >= NBUCK) {
        gemm_f32_body(blockIdx.x - NBUCK, x, wp1, u);
        return;
    }
    __shared__ int cnt[NBUCK];
    __shared__ int basebuf[NBUCK];
    int t = threadIdx.x;
    int e0 = blockIdx.x * CHUNK;
    for (int i = t; i < NBUCK; i += 256) cnt[i] = 0;
    __syncthreads();
    unsigned pk[16]; int bk[16];
#pragma unroll
    for (int j = 0; j < 16; ++j) {
        int e = e0 + j * 256 + t;
        if (e < N_EDGES) {
            int s = src[e], d = dst[e];
            bk[j] = d >> 8;
            pk[j] = ((unsigned)s << 8) | (unsigned)(d & 255);
            atomicAdd(&cnt[bk[j]], 1);
        } else bk[j] = -1;
    }
    __syncthreads();
    for (int i = t; i < NBUCK; i += 256) {
        int c = cnt[i];
        basebuf[i] = c ? atomicAdd(&bcur[i], c) : 0;
        cnt[i] = 0;
    }
    __syncthreads();
#pragma unroll
    for (int j = 0; j < 16; ++j) {
        if (bk[j] >= 0) {
            int p = basebuf[bk[j]] + atomicAdd(&cnt[bk[j]], 1);
            pairs[p] = pk[j];
        }
    }
}

// ---------------- dispatch 4: fused deg+dinv+offs+csr fill (blocks 0..390) + gemm1 tiles 781..1562 ----
__global__ __launch_bounds__(256) void k_bfill_g1(const unsigned int* __restrict__ pairs,
                                                  const int* __restrict__ bbase,
                                                  const int* __restrict__ bcount,
                                                  float* __restrict__ dinv,
                                                  int* __restrict__ offs,
                                                  int* __restrict__ csr,
                                                  const float* __restrict__ x,
                                                  const unsigned short* __restrict__ wp1,
                                                  unsigned short* __restrict__ u) {
    if (blockIdx.x >= NBUCK) {
        gemm_f32_body(blockIdx.x - NBUCK + G1A, x, wp1, u);
        return;
    }
    __shared__ int degl[256];
    __shared__ int lcur[256];
    __shared__ int ws[4];
    int b = blockIdx.x, t = threadIdx.x;
    degl[t] = 0;
    __syncthreads();
    int s0 = bbase[b], n = bcount[b];
    for (int i = t; i < n; i += 256) atomicAdd(&degl[pairs[s0 + i] & 255u], 1);
    __syncthreads();
    int node = b * 256 + t;
    int dv = degl[t];
    if (node < N_NODES) dinv[node] = rsqrtf((float)(dv + 1));  // +1 self-loop
    int lane = t & 63, wid = t >> 6;
    int s = dv;
#pragma unroll
    for (int d = 1; d < 64; d <<= 1) { int nn = __shfl_up(s, d); if (lane >= d) s += nn; }
    if (lane == 63) ws[wid] = s;
    __syncthreads();
    if (t < 4) {
        int xx = ws[t];
#pragma unroll
        for (int d = 1; d < 4; d <<= 1) { int nn = __shfl_up(xx, d); if ((int)t >= d) xx += nn; }
        ws[t] = xx;
    }
    __syncthreads();
    int excl = s - dv + (wid ? ws[wid - 1] : 0) + bbase[b];  // wbase == bbase
    if (node < N_NODES) offs[node] = excl;
    lcur[t] = excl;
    __syncthreads();
    for (int i = t; i < n; i += 256) {
        unsigned pr = pairs[s0 + i];
        int p = atomicAdd(&lcur[pr & 255u], 1);
        csr[p] = (int)(pr >> 8);
    }
}

// ---------------- gemm2: bf16 hi/lo plane input, unscaled u out ----------------
__global__ __launch_bounds__(256) void k_gemm_mfma_bf(const unsigned short* __restrict__ hh,
                                                      const unsigned short* __restrict__ hl,
                                                      const unsigned short* __restrict__ wp,
                                                      unsigned short* __restrict__ u) {
    __shared__ unsigned short sW[32768];
    {
        float4* d4 = (float4*)sW;
        const float4* s4 = (const float4*)wp;
#pragma unroll
        for (int i = 0; i < 16; ++i) d4[threadIdx.x + 256 * i] = s4[threadIdx.x + 256 * i];
    }
    __syncthreads();
    const int t = threadIdx.x;
    const int wv = t >> 6, L = t & 63;
    const int m = L & 15, q = L >> 4;
    const int r0 = blockIdx.x * 64 + wv * 16;
    int arow = r0 + m;
    if (arow >= N_NODES) arow = N_NODES - 1;
    const unsigned short* hhp = hh + (size_t)arow * 128 + 8 * q;
    const unsigned short* hlp = hl + (size_t)arow * 128 + 8 * q;
    float4v acc[8];
#pragma unroll
    for (int c = 0; c < 8; ++c) acc[c] = (float4v){0.f, 0.f, 0.f, 0.f};
#pragma unroll
    for (int k0 = 0; k0 < 128; k0 += 32) {
        short8 ah = *(const short8*)(hhp + k0);
        short8 al = *(const short8*)(hlp + k0);
        const int b = (k0 >> 3) + q;
#pragma unroll
        for (int c = 0; c < 8; ++c) {
            int ng = c * 16 + m;
            int elem = ng * 128 + 8 * ((b ^ ng) & 15);
            short8 bh = *(const short8*)&sW[elem];
            short8 bl = *(const short8*)&sW[16384 + elem];
            acc[c] = __builtin_amdgcn_mfma_f32_16x16x32_bf16(ah, bh, acc[c], 0, 0, 0);
            acc[c] = __builtin_amdgcn_mfma_f32_16x16x32_bf16(al, bh, acc[c], 0, 0, 0);
            acc[c] = __builtin_amdgcn_mfma_f32_16x16x32_bf16(ah, bl, acc[c], 0, 0, 0);
        }
    }
#pragma unroll
    for (int r = 0; r < 4; ++r) {
        int row = r0 + 4 * q + r;
        if (row < N_NODES) {
            unsigned short* up = u + (size_t)row * 128 + m;
#pragma unroll
            for (int c = 0; c < 8; ++c) up[c * 16] = f2bf(acc[c][r]);
        }
    }
}

// ---------------- aggregate: h = relu(dinv_i*(sum dinv_s*u[s] + dinv_i*u[i]) + b) ----------------
// u is UNSCALED; dinv applied per edge via scalar loads.
// Gather restructured: ONE global_load_dwordx4 fetches 4 edges' rows (16 lanes x 16 B per row;
// lane L -> edge L>>4, cols 8*(L&15)..+7). 4x fewer VMEM gather instructions per edge vs
// dword-per-lane. Partials reduced across the 4 edge-groups with shfl_xor(16)/shfl_xor(32).
// hlp != nullptr: emit hi/lo bf16 planes (feeds gemm2). hlp == nullptr: single bf16 plane (pool).
__global__ __launch_bounds__(256) void k_agg(const unsigned int* __restrict__ u,
                                             const int* __restrict__ offs,
                                             const int* __restrict__ csr,
                                             const float* __restrict__ dinv,
                                             const float* __restrict__ bias,
                                             unsigned int* __restrict__ hhp,
                                             unsigned int* __restrict__ hlp) {
    int wid = threadIdx.x >> 6;
    int lane = threadIdx.x & 63;
    int node = __builtin_amdgcn_readfirstlane(blockIdx.x * 4 + wid);
    if (node >= N_NODES) return;
    int p = __builtin_amdgcn_readfirstlane(offs[node]);
    int e = __builtin_amdgcn_readfirstlane(offs[node + 1]);
    const int g = lane >> 4;    // edge-group 0..3 within the wave
    const int sl = lane & 15;   // col-group: cols 8*sl .. 8*sl+7
    float dsf = dinv[node];

    // self row: one dwordx4 per lane; groups redundantly read the same 16 B (single coalesced
    // instruction); only group 0 weights it so the 4-way reduce counts it once.
    uint4 sv = *(const uint4*)(u + (size_t)node * 64 + 4 * sl);
    float wself = (g == 0) ? dsf : 0.f;
    float acc[8];
    acc[0] = wself * bf_lo(sv.x); acc[1] = wself * bf_hi(sv.x);
    acc[2] = wself * bf_lo(sv.y); acc[3] = wself * bf_hi(sv.y);
    acc[4] = wself * bf_lo(sv.z); acc[5] = wself * bf_hi(sv.z);
    acc[6] = wself * bf_lo(sv.w); acc[7] = wself * bf_hi(sv.w);

    for (; p < e; p += 8) {
        int c0 = csr[p + 0], c1 = csr[p + 1], c2 = csr[p + 2], c3 = csr[p + 3];
        int c4 = csr[p + 4], c5 = csr[p + 5], c6 = csr[p + 6], c7 = csr[p + 7];
        int i0 = c0;
        int i1 = (p + 1 < e) ? c1 : N_NODES;
        int i2 = (p + 2 < e) ? c2 : N_NODES;
        int i3 = (p + 3 < e) ? c3 : N_NODES;
        int i4 = (p + 4 < e) ? c4 : N_NODES;
        int i5 = (p + 5 < e) ? c5 : N_NODES;
        int i6 = (p + 6 < e) ? c6 : N_NODES;
        int i7 = (p + 7 < e) ? c7 : N_NODES;
        float d0 = dinv[i0], d1 = dinv[i1], d2 = dinv[i2], d3 = dinv[i3];
        float d4 = dinv[i4], d5 = dinv[i5], d6 = dinv[i6], d7 = dinv[i7];
        // per-lane edge select for the two 4-edge vector gathers
        int ia = (g == 0) ? i0 : (g == 1) ? i1 : (g == 2) ? i2 : i3;
        int ib = (g == 0) ? i4 : (g == 1) ? i5 : (g == 2) ? i6 : i7;
        float da = (g == 0) ? d0 : (g == 1) ? d1 : (g == 2) ? d2 : d3;
        float db = (g == 0) ? d4 : (g == 1) ? d5 : (g == 2) ? d6 : d7;
        uint4 va = *(const uint4*)(u + (size_t)ia * 64 + 4 * sl);
        uint4 vb = *(const uint4*)(u + (size_t)ib * 64 + 4 * sl);
        acc[0] = fmaf(da, bf_lo(va.x), acc[0]); acc[1] = fmaf(da, bf_hi(va.x), acc[1]);
        acc[2] = fmaf(da, bf_lo(va.y), acc[2]); acc[3] = fmaf(da, bf_hi(va.y), acc[3]);
        acc[4] = fmaf(da, bf_lo(va.z), acc[4]); acc[5] = fmaf(da, bf_hi(va.z), acc[5]);
        acc[6] = fmaf(da, bf_lo(va.w), acc[6]); acc[7] = fmaf(da, bf_hi(va.w), acc[7]);
        acc[0] = fmaf(db, bf_lo(vb.x), acc[0]); acc[1] = fmaf(db, bf_hi(vb.x), acc[1]);
        acc[2] = fmaf(db, bf_lo(vb.y), acc[2]); acc[3] = fmaf(db, bf_hi(vb.y), acc[3]);
        acc[4] = fmaf(db, bf_lo(vb.z), acc[4]); acc[5] = fmaf(db, bf_hi(vb.z), acc[5]);
        acc[6] = fmaf(db, bf_lo(vb.w), acc[6]); acc[7] = fmaf(db, bf_hi(vb.w), acc[7]);
    }

    // reduce the 4 edge-group partials (butterfly: all lanes end with full sums)
#pragma unroll
    for (int k = 0; k < 8; ++k) {
        acc[k] += __shfl_xor(acc[k], 16);
        acc[k] += __shfl_xor(acc[k], 32);
    }

    const float4* bp = (const float4*)bias;
    float4 b0 = bp[2 * sl], b1 = bp[2 * sl + 1];
    float r[8];
    r[0] = fmaxf(dsf * acc[0] + b0.x, 0.f);
    r[1] = fmaxf(dsf * acc[1] + b0.y, 0.f);
    r[2] = fmaxf(dsf * acc[2] + b0.z, 0.f);
    r[3] = fmaxf(dsf * acc[3] + b0.w, 0.f);
    r[4] = fmaxf(dsf * acc[4] + b1.x, 0.f);
    r[5] = fmaxf(dsf * acc[5] + b1.y, 0.f);
    r[6] = fmaxf(dsf * acc[6] + b1.z, 0.f);
    r[7] = fmaxf(dsf * acc[7] + b1.w, 0.f);

    if (hlp) {
        unsigned hv[4], lv[4];
#pragma unroll
        for (int j = 0; j < 4; ++j) {
            unsigned ue = __float_as_uint(r[2 * j]), uo = __float_as_uint(r[2 * j + 1]);
            unsigned short he = (unsigned short)(ue >> 16), ho = (unsigned short)(uo >> 16);
            float fe = __uint_as_float(ue & 0xFFFF0000u), fo = __uint_as_float(uo & 0xFFFF0000u);
            unsigned short le = f2bf(r[2 * j] - fe), lo2 = f2bf(r[2 * j + 1] - fo);
            hv[j] = (unsigned)he | ((unsigned)ho << 16);
            lv[j] = (unsigned)le | ((unsigned)lo2 << 16);
        }
        uint4 hq = {hv[0], hv[1], hv[2], hv[3]};
        uint4 lq = {lv[0], lv[1], lv[2], lv[3]};
        if (g == 0) *(uint4*)(hhp + (size_t)node * 64 + 4 * sl) = hq;
        if (g == 1) *(uint4*)(hlp + (size_t)node * 64 + 4 * sl) = lq;
    } else {
        if (g == 0) {
            unsigned hv[4];
#pragma unroll
            for (int j = 0; j < 4; ++j)
                hv[j] = (unsigned)f2bf(r[2 * j]) | ((unsigned)f2bf(r[2 * j + 1]) << 16);
            uint4 hq = {hv[0], hv[1], hv[2], hv[3]};
            *(uint4*)(hhp + (size_t)node * 64 + 4 * sl) = hq;
        }
    }
}

// ---------------- pool (batch sorted) + linear head; h = single bf16 plane ----------------
__global__ __launch_bounds__(128) void k_pool(const unsigned short* __restrict__ hh,
                                              const int* __restrict__ batch,
                                              const float* __restrict__ Wl,
                                              const float* __restrict__ bl,
                                              float* __restrict__ out) {
    int g = blockIdx.x;
    int c = threadIdx.x;
    __shared__ int sb[2];
    if (c < 2) {
        int tgt = g + c;
        int lo = 0, hi = N_NODES;
        while (lo < hi) { int m = (lo + hi) >> 1; if (batch[m] < tgt) lo = m + 1; else hi = m; }
        sb[c] = lo;
    }
    __syncthreads();
    int s0 = sb[0], s1 = sb[1];
    float sum = 0.f;
    for (int i = s0; i < s1; ++i) sum += bf_s(hh[(size_t)i * 128 + c]);
    float cnt = (float)(s1 - s0);
    float pooled = sum / fmaxf(cnt, 1.0f);
    __shared__ float red[128];
    float w0 = Wl[c * 2 + 0], w1 = Wl[c * 2 + 1];
    red[c] = pooled * w0;
    __syncthreads();
    for (int st = 64; st > 0; st >>= 1) { if (c < st) red[c] += red[c + st]; __syncthreads(); }
    if (c == 0) out[g * 2 + 0] = red[0] + bl[0];
    __syncthreads();
    red[c] = pooled * w1;
    __syncthreads();
    for (int st = 64; st > 0; st >>= 1) { if (c < st) red[c] += red[c + st]; __syncthreads(); }
    if (c == 0) out[g * 2 + 1] = red[0] + bl[1];
}

extern "C" void kernel_launch(void* const* d_in, const int* in_sizes, int n_in,
                              void* d_out, int out_size, void* d_ws, size_t ws_size,
                              hipStream_t stream) {
    const float* x  = (const float*)d_in[0];
    const int* ei   = (const int*)d_in[1];
    const int* batch = (const int*)d_in[2];
    const float* W1 = (const float*)d_in[3];
    const float* b1 = (const float*)d_in[4];
    const float* W2 = (const float*)d_in[5];
    const float* b2 = (const float*)d_in[6];
    const float* Wl = (const float*)d_in[7];
    const float* bl = (const float*)d_in[8];
    float* out = (float*)d_out;
    const int* src = ei;
    const int* dst = ei + N_EDGES;

    char* ws = (char*)d_ws;
    size_t o = 0;
    auto alloc = [&](size_t bytes) -> void* {
        o = (o + 255) & ~(size_t)255;
        void* p = ws + o;
        o += bytes;
        return p;
    };
    int* bcount = (int*)alloc((size_t)NBUCK * 4);
    int* bbase  = (int*)alloc((size_t)NBUCK * 4);
    int* bcur   = (int*)alloc((size_t)NBUCK * 4);
    float* dinv = (float*)alloc((size_t)(N_NODES + 1) * 4);  // +1 zero slot for tail
    int* offs   = (int*)alloc((size_t)(N_NODES + 1) * 4);
    unsigned short* wp1 = (unsigned short*)alloc(65536);
    unsigned short* wp2 = (unsigned short*)alloc(65536);
    unsigned int* pairs = (unsigned int*)alloc((size_t)N_EDGES * 4);
    int* csr    = (int*)alloc((size_t)(N_EDGES + 8) * 4);               // +8 pad for unroll reads
    unsigned short* u = (unsigned short*)alloc((size_t)(N_NODES + 1) * 128 * 2);  // +1 zero row
    unsigned short* hh = (unsigned short*)alloc((size_t)N_NODES * 128 * 2);
    unsigned short* hl = (unsigned short*)alloc((size_t)N_NODES * 128 * 2);

    hipMemsetAsync(bcount, 0, (size_t)NBUCK * 4, stream);
    k_prep_hist<<<384, 256, 0, stream>>>(W1, W2, wp1, wp2, dst, bcount,
                                         (unsigned int*)(u + (size_t)N_NODES * 128), dinv);
    k_scan391<<<1, 512, 0, stream>>>(bcount, bbase, bcur, &offs[N_NODES]);
    k_bucket_g1<<<NBUCK + G1A, 256, 0, stream>>>(src, dst, bcur, pairs, x, wp1, u);
    k_bfill_g1<<<NBUCK + G1B, 256, 0, stream>>>(pairs, bbase, bcount, dinv, offs, csr, x, wp1, u);

    k_agg<<<(N_NODES + 3) / 4, 256, 0, stream>>>((const unsigned int*)u, offs, csr, dinv, b1,
                                                 (unsigned int*)hh, (unsigned int*)hl);
    k_gemm_mfma_bf<<<NTILES, 256, 0, stream>>>(hh, hl, wp2, u);
    k_agg<<<(N_NODES + 3) / 4, 256, 0, stream>>>((const unsigned int*)u, offs, csr, dinv, b2,
                                                 (unsigned int*)hh, nullptr);

    k_pool<<<N_GRAPHS, 128, 0, stream>>>(hh, batch, Wl, bl, out);
}